// Round 1
// baseline (143.518 us; speedup 1.0000x reference)
//
#include <hip/hip_runtime.h>
#include <math.h>

// Constants (computed at double precision, truncated to f32 literals)
#define RG_F     (8.3144621f / 96487.0f)          // R_GAS / F
#define INV_F    (1.0f / 96487.0f)
#define INV_SN   (1.0f / 0.000437545f)
#define INV_SP   (1.0f / 0.00030962f)
#define KN_C     2120.96f
#define KP_C     248898.0f
#define RO_C     0.117215f
#define INV_TDIFF (1.0f / 7000000.0f)
#define INV_TO   (1.0f / 6.08671f)
#define INV_TSN  (1.0f / 1001.38f)
#define INV_TSP  (1.0f / 46.4311f)
#define U0P_C    4.03f
#define U0N_C    0.01f
#define INV_VOLB (1.0f / 1.8e-05f)
#define INV_VOLS (1.0f / 2.0e-06f)
#define INV_QSMAX (1.0f / 1266.6666666666667f)    // 1 / (Q_MAX * VOL_S / VOL)

__device__ __forceinline__ float ve_sum_p(float x) {
    // AP polynomial: sum_k A[k]*pw*(m2 - tx*k), pw = m^(k-1), then /F
    const float A1  = 0.106747f,   A2  = 24606.4f,   A3 = -78561.9f;
    const float A4  = 13317.9f,    A5  = 307387.0f,  A6 = 84916.1f;
    const float A7  = -1074690.0f, A8  = 2285.04f,   A9 = 990894.0f;
    const float A10 = 283920.0f,   A11 = -161513.0f, A12 = -469218.0f;
    const float A0  = -31593.7f;

    float m  = 2.0f * x - 1.0f;
    float m2 = m * m;
    float tx = 2.0f * x * (1.0f - x);
    float s  = A0 * m;
    float pw = 1.0f;
    s = fmaf(A1  * pw, m2 - tx * 1.0f,  s); pw *= m;
    s = fmaf(A2  * pw, m2 - tx * 2.0f,  s); pw *= m;
    s = fmaf(A3  * pw, m2 - tx * 3.0f,  s); pw *= m;
    s = fmaf(A4  * pw, m2 - tx * 4.0f,  s); pw *= m;
    s = fmaf(A5  * pw, m2 - tx * 5.0f,  s); pw *= m;
    s = fmaf(A6  * pw, m2 - tx * 6.0f,  s); pw *= m;
    s = fmaf(A7  * pw, m2 - tx * 7.0f,  s); pw *= m;
    s = fmaf(A8  * pw, m2 - tx * 8.0f,  s); pw *= m;
    s = fmaf(A9  * pw, m2 - tx * 9.0f,  s); pw *= m;
    s = fmaf(A10 * pw, m2 - tx * 10.0f, s); pw *= m;
    s = fmaf(A11 * pw, m2 - tx * 11.0f, s); pw *= m;
    s = fmaf(A12 * pw, m2 - tx * 12.0f, s);
    return s * INV_F;
}

__global__ __launch_bounds__(256) void battery_rnn_kernel(
    const float* __restrict__ cur,     // inputs  (B,1)
    const float* __restrict__ states,  // states  (B,8)
    float* __restrict__ outZ,          // Z       (B,2)
    float* __restrict__ outX,          // X_next  (B,8)
    int n)
{
    int idx = blockIdx.x * blockDim.x + threadIdx.x;
    if (idx >= n) return;

    const float4 s0 = *reinterpret_cast<const float4*>(states + (size_t)idx * 8);
    const float4 s1 = *reinterpret_cast<const float4*>(states + (size_t)idx * 8 + 4);
    const float i   = cur[idx];

    const float Tb  = s0.x, Vo  = s0.y, Vsn = s0.z, Vsp = s0.w;
    const float qnB = s1.x, qnS = s1.y, qpB = s1.z, qpS = s1.w;

    // surface mole fractions (pre-step)
    const float xnS = qnS * INV_QSMAX;
    const float xpS = qpS * INV_QSMAX;

    // diffusion rates
    const float qdDn = (qnB * INV_VOLB - qnS * INV_VOLS) * INV_TDIFF;
    const float qdDp = (qpB * INV_VOLB - qpS * INV_VOLS) * INV_TDIFF;

    // exchange currents: K * (1-x)^0.5 * x^0.5 = K * sqrt(x*(1-x))
    const float Jn0 = KN_C * sqrtf(xnS * (1.0f - xnS));
    const float Jp0 = KP_C * sqrtf(xpS * (1.0f - xpS));

    const float Jn = i * INV_SN;
    const float Jp = i * INV_SP;

    // R*Tb/F/alpha, alpha = 0.5 -> 2*R*Tb/F
    const float rtfa = 2.0f * RG_F * Tb;
    const float VsnNom = rtfa * asinhf(Jn / (2.0f * Jn0));
    const float VspNom = rtfa * asinhf(Jp / (2.0f * Jp0));

    // state update (DT = 1)
    const float Vo_n  = Vo  + (i * RO_C  - Vo ) * INV_TO;
    const float Vsn_n = Vsn + (VsnNom    - Vsn) * INV_TSN;
    const float Vsp_n = Vsp + (VspNom    - Vsp) * INV_TSP;
    const float qnB_n = qnB - qdDn;
    const float qnS_n = qnS + (qdDn - i);
    const float qpB_n = qpB - qdDp;
    const float qpS_n = qpS + (i + qdDp);

    // post-step surface fractions
    const float xn2 = qnS_n * INV_QSMAX;
    const float xp2 = qpS_n * INV_QSMAX;

    const float rtf = RG_F * Tb;
    // Ven: AN poly reduces to A0*m/F since AN[1..12] == 0
    const float Ven = U0N_C + rtf * logf((1.0f - xn2) / xn2)
                    + 86.19f * (2.0f * xn2 - 1.0f) * INV_F;
    const float Vep = U0P_C + rtf * logf((1.0f - xp2) / xp2)
                    + ve_sum_p(xp2);

    const float V = Vep - Ven - Vo_n - Vsn_n - Vsp_n;

    // stores: Z (B,2) then X_next (B,8)
    *reinterpret_cast<float2*>(outZ + (size_t)idx * 2) =
        make_float2(Tb - 273.15f, V);
    *reinterpret_cast<float4*>(outX + (size_t)idx * 8) =
        make_float4(Tb, Vo_n, Vsn_n, Vsp_n);
    *reinterpret_cast<float4*>(outX + (size_t)idx * 8 + 4) =
        make_float4(qnB_n, qnS_n, qpB_n, qpS_n);
}

extern "C" void kernel_launch(void* const* d_in, const int* in_sizes, int n_in,
                              void* d_out, int out_size, void* d_ws, size_t ws_size,
                              hipStream_t stream) {
    const float* cur    = (const float*)d_in[0];   // inputs (B,1)
    const float* states = (const float*)d_in[1];   // states (B,8)
    const int n = in_sizes[0];                      // B

    float* outZ = (float*)d_out;                    // first B*2 floats
    float* outX = (float*)d_out + 2 * (size_t)n;    // next  B*8 floats

    const int block = 256;
    const int grid  = (n + block - 1) / block;
    battery_rnn_kernel<<<grid, block, 0, stream>>>(cur, states, outZ, outX, n);
}